// Round 1
// baseline (457.421 us; speedup 1.0000x reference)
//
#include <hip/hip_runtime.h>

#define HH 512
#define WW 512
// sigmoid(10*t) = 1/(1 + 2^(-10*log2(e)*t));  KSL = 10*log2(e)
#define KSL 14.426950408889634f

typedef float f4 __attribute__((ext_vector_type(4)));

// sigmoid(10*t) where arg == -KSL*t : one v_exp_f32 + one v_rcp_f32
__device__ __forceinline__ float sig_arg(float arg) {
    float e = __builtin_amdgcn_exp2f(arg);
    return __builtin_amdgcn_rcpf(1.0f + e);
}

// One block = one (batch, channel) pair, 4 rows x 256 cols.
// grid.z = b*3 + c  -> per-thread work cut 3x vs the all-channel version,
// window registers 72 -> ~50, shorter waves for trans-latency hiding.
__global__ __launch_bounds__(256, 3) void edge_kernel(const float* __restrict__ x,
                                                      float* __restrict__ out) {
    const int tx = threadIdx.x & 63;          // 64 lanes along w, 4 px each
    const int ty = threadIdx.x >> 6;          // 4 rows per block
    const int w0 = blockIdx.x * 256 + tx * 4; // aligned float4 start
    const int h  = blockIdx.y * 4 + ty;
    const int z  = blockIdx.z;                // z = b*3 + c
    const int b  = z / 3;
    const int c  = z - 3 * b;

    float* outp = out + (((size_t)(b * 24 + c * 8) * HH + h) * WW + w0);
    const int PL = HH * WW;                   // plane stride in floats

    // h-exterior rows are entirely zero: wave-uniform branch
    if (h < 2 || h >= HH - 2) {
        const f4 zf = {0.f, 0.f, 0.f, 0.f};
        #pragma unroll
        for (int k = 0; k < 8; ++k)
            __builtin_nontemporal_store(zf, (f4*)(outp + k * PL));
        return;
    }

    const int cm = (c + 2) % 3, cp = (c + 1) % 3;
    const int wl = (w0 == 0) ? 0 : (w0 - 1);
    const int wr = (w0 + 4 >= WW) ? (WW - 1) : (w0 + 4);

    const float* bas = x + (size_t)b * 3 * HH * WW + (size_t)(h - 2) * WW;

    // Windows: S = self channel rows h-2..h+1, M = c-1 rows h-2..h,
    // P = c+1 rows h-2..h. Only the elements actually consumed are loaded
    // (halo trimming: S row0 none, M row1 none, P left-only rows 0/2).
    float S[4][6], M[3][6], P[3][6];
    {
        const float* rp = bas + (size_t)c * (HH * WW);
        #pragma unroll
        for (int r = 0; r < 4; ++r) {
            const float* row = rp + r * WW;
            const f4 m = *(const f4*)(row + w0);
            S[r][1] = m.x; S[r][2] = m.y; S[r][3] = m.z; S[r][4] = m.w;
            if (r > 0) { S[r][0] = row[wl]; S[r][5] = row[wr]; }
        }
    }
    {
        const float* rp = bas + (size_t)cm * (HH * WW);
        #pragma unroll
        for (int r = 0; r < 3; ++r) {
            const float* row = rp + r * WW;
            const f4 m = *(const f4*)(row + w0);
            M[r][1] = m.x; M[r][2] = m.y; M[r][3] = m.z; M[r][4] = m.w;
            if (r != 1) { M[r][0] = row[wl]; M[r][5] = row[wr]; }
        }
    }
    {
        const float* rp = bas + (size_t)cp * (HH * WW);
        #pragma unroll
        for (int r = 0; r < 3; ++r) {
            const float* row = rp + r * WW;
            const f4 m = *(const f4*)(row + w0);
            P[r][1] = m.x; P[r][2] = m.y; P[r][3] = m.z; P[r][4] = m.w;
            if (r != 1) { P[r][0] = row[wl]; }   // right halo never used
        }
    }

    float acc[8][4];
    #pragma unroll
    for (int q = 0; q < 4; ++q) {
        const float v = S[2][q + 1], u = S[1][q + 1];
        const float d10   = u           - v;   // x[h-1,w]   - x
        const float dn10  = S[3][q + 1] - v;   // x[h+1,w]   - x
        const float d01   = S[2][q]     - v;   // x[h,w-1]   - x
        const float dn01  = S[2][q + 2] - v;   // x[h,w+1]   - x
        const float d11   = S[1][q]     - v;   // x[h-1,w-1] - x
        const float dnn11 = S[3][q + 2] - v;   // x[h+1,w+1] - x
        const float dn11  = S[3][q]     - v;   // x[h+1,w-1] - x
        const float d1n1  = S[1][q + 2] - v;   // x[h-1,w+1] - x
        const float r_d10 = S[0][q + 1] - u;   // diff_10 @ (h-1,w)
        const float r_d01 = S[1][q]     - u;   // diff_01 @ (h-1,w)

        // cross-channel neighbor diffs (channel rolls in the reference)
        const float A01m   = fabsf(M[2][q]     - M[2][q + 1]);
        const float An01m  = fabsf(M[2][q + 2] - M[2][q + 1]);
        const float rA11m  = fabsf(M[0][q]     - M[1][q + 1]);
        const float rAn11m = fabsf(M[2][q]     - M[1][q + 1]);
        const float rA1n1m = fabsf(M[0][q + 2] - M[1][q + 1]);
        const float rA11p  = fabsf(P[0][q]     - P[1][q + 1]);
        const float rAn11p = fabsf(P[2][q]     - P[1][q + 1]);

        // w-exterior pixels are zeroed via the g gates
        const float msk = ((w0 + q) >= 2 && (w0 + q) < WW - 2) ? 1.0f : 0.0f;

        // ---- branch 10 ----
        const float a10  = fabsf(d10);
        const float sa10 = sig_arg(a10 * -KSL);
        const float ad10 = a10 * sa10;
        const float b10  = ad10 * -KSL;        // shared fma base: -K*ad10
        const float e10s = sig_arg(fmaf(fabsf(d01),  KSL, b10))
                         + sig_arg(fmaf(fabsf(dn01), KSL, b10))
                         + sig_arg(fmaf(fabsf(dn10), KSL, b10))
                         + 2.0f * sig_arg(fmaf(A01m, KSL, b10))   // repeated in ref
                         + sig_arg(fmaf(An01m, KSL, b10));
        const float g10 = msk * sig_arg(fmaf(e10s, -KSL, 4.0f * KSL));
        const float s10 = sig_arg(d10 * -KSL);
        acc[0][q] = g10 * s10;
        acc[1][q] = fmaf(-s10, g10, g10);       // g*(1-s)

        // ---- branch 01 ---- (scaled by sigm(ad_10); its arg IS b10)
        const float sad10 = sig_arg(b10);
        const float ad01  = fabsf(d01) * sad10;
        const float b01   = ad01 * -KSL;
        const float e01s = 2.0f * sig_arg(fmaf(a10, KSL, b01))     // term twice
                         + sig_arg(fmaf(fabsf(dn10),  KSL, b01))
                         + sig_arg(fmaf(fabsf(dn01),  KSL, b01))
                         + sig_arg(fmaf(fabsf(r_d10), KSL, b01))
                         + sig_arg(fmaf(fabsf(r_d01), KSL, b01));
        const float g01 = msk * sig_arg(fmaf(e01s, -KSL, 4.0f * KSL));
        const float e01 = g01 * sig_arg(d01 * -KSL);
        acc[2][q] = e01;
        acc[3][q] = e01;                        // ref: e01n == e01

        // ---- branch 11 ----
        const float a11  = fabsf(d11);
        const float sa11 = sig_arg(a11 * -KSL);
        const float ad11 = a11 * sa11;
        const float b11  = ad11 * -KSL;
        const float e11s = sig_arg(fmaf(fabsf(dn11),  KSL, b11))
                         + sig_arg(fmaf(fabsf(d1n1),  KSL, b11))
                         + sig_arg(fmaf(fabsf(dnn11), KSL, b11))
                         + sig_arg(fmaf(rAn11m, KSL, b11))
                         + sig_arg(fmaf(rA1n1m, KSL, b11))
                         + sig_arg(fmaf(rA11m,  KSL, b11));
        const float g11 = msk * sig_arg(fmaf(e11s, -KSL, 4.0f * KSL));
        const float s11 = sig_arg(d11 * -KSL);
        acc[4][q] = g11 * s11;
        acc[5][q] = fmaf(-s11, g11, g11);

        // ---- branch n11 ---- (hard >0 mask is identity)
        const float adn11 = fabsf(dn11);
        const float bn11  = adn11 * -KSL;
        const float en11s = sig_arg(fmaf(a11, KSL, bn11))
                          + sig_arg(fmaf(fabsf(d1n1),  KSL, bn11))
                          + sig_arg(fmaf(fabsf(dnn11), KSL, bn11))
                          + sig_arg(fmaf(rA11p, KSL, bn11))
                          + 2.0f * sig_arg(fmaf(rAn11p, KSL, bn11)); // repeated
        const float gn11 = msk * sig_arg(fmaf(en11s, -KSL, 4.0f * KSL));
        const float sn11 = sig_arg(dn11 * -KSL);
        acc[6][q] = gn11 * sn11;
        acc[7][q] = fmaf(-sn11, gn11, gn11);
    }

    #pragma unroll
    for (int k = 0; k < 8; ++k) {
        const f4 o = {acc[k][0], acc[k][1], acc[k][2], acc[k][3]};
        __builtin_nontemporal_store(o, (f4*)(outp + k * PL));
    }
}

extern "C" void kernel_launch(void* const* d_in, const int* in_sizes, int n_in,
                              void* d_out, int out_size, void* d_ws, size_t ws_size,
                              hipStream_t stream) {
    const float* x = (const float*)d_in[0];
    float* out = (float*)d_out;
    dim3 grid(WW / 256, HH / 4, 16 * 3);  // (2, 128, 48): z = b*3 + c
    dim3 block(256);                      // wave = 64 lanes x 4 px
    edge_kernel<<<grid, block, 0, stream>>>(x, out);
}

// Round 2
// 448.101 us; speedup vs baseline: 1.0208x; 1.0208x over previous
//
#include <hip/hip_runtime.h>

#define HH 512
#define WW 512
// sigmoid(10*t) = 1/(1 + 2^(-K*t));  K = 10*log2(e)
#define KSL 14.426950408889634f
#define FOURK 57.707801635558536f   // 4*KSL

typedef float f4 __attribute__((ext_vector_type(4)));

// sigmoid(10*t) where arg == -K*t : one v_exp_f32 + one v_rcp_f32
__device__ __forceinline__ float sig_arg(float arg) {
    float e = __builtin_amdgcn_exp2f(arg);
    return __builtin_amdgcn_rcpf(1.0f + e);
}
// Q = 2^(K*|x|)  (abs is a free src modifier on the mul consumer)
__device__ __forceinline__ float QE(float x) {
    return __builtin_amdgcn_exp2f(KSL * fabsf(x));
}
// one inner-sum term: sigm(ad - X) = rcp(1 + Q_X * P_ad)
__device__ __forceinline__ float term(float qx, float p) {
    return __builtin_amdgcn_rcpf(fmaf(qx, p, 1.0f));
}

__global__ __launch_bounds__(256, 2) void edge_kernel(const float* __restrict__ x,
                                                      float* __restrict__ out) {
    const int tx = threadIdx.x & 63;          // 64 lanes along w, 4 px each
    const int ty = threadIdx.x >> 6;          // 4 rows per block
    const int w0 = blockIdx.x * 256 + tx * 4; // aligned float4 start
    const int h  = blockIdx.y * 4 + ty;
    const int z  = blockIdx.z;                // z = b*3 + c
    const int b  = z / 3;
    const int c  = z - 3 * b;

    float* outp = out + (((size_t)(b * 24 + c * 8) * HH + h) * WW + w0);
    const int PL = HH * WW;                   // plane stride in floats

    if (h < 2 || h >= HH - 2) {               // h-exterior rows: all zero
        const f4 zf = {0.f, 0.f, 0.f, 0.f};
        #pragma unroll
        for (int k = 0; k < 8; ++k)
            __builtin_nontemporal_store(zf, (f4*)(outp + k * PL));
        return;
    }

    const int cm = (c + 2) % 3, cp = (c + 1) % 3;
    const int wl = (w0 == 0) ? 0 : (w0 - 1);
    const int wr = (w0 + 4 >= WW) ? (WW - 1) : (w0 + 4);

    const float* bas = x + (size_t)b * 3 * HH * WW + (size_t)(h - 2) * WW;

    // S = self channel rows h-2..h+1, M = c-1 rows h-2..h, P = c+1 rows h-2..h
    float S[4][6], M[3][6], P[3][6];
    {
        const float* rp = bas + (size_t)c * (HH * WW);
        #pragma unroll
        for (int r = 0; r < 4; ++r) {
            const float* row = rp + r * WW;
            const f4 m = *(const f4*)(row + w0);
            S[r][1] = m.x; S[r][2] = m.y; S[r][3] = m.z; S[r][4] = m.w;
            if (r > 0) { S[r][0] = row[wl]; S[r][5] = row[wr]; }
        }
    }
    {
        const float* rp = bas + (size_t)cm * (HH * WW);
        #pragma unroll
        for (int r = 0; r < 3; ++r) {
            const float* row = rp + r * WW;
            const f4 m = *(const f4*)(row + w0);
            M[r][1] = m.x; M[r][2] = m.y; M[r][3] = m.z; M[r][4] = m.w;
            if (r != 1) { M[r][0] = row[wl]; M[r][5] = row[wr]; }
        }
    }
    {
        const float* rp = bas + (size_t)cp * (HH * WW);
        #pragma unroll
        for (int r = 0; r < 3; ++r) {
            const float* row = rp + r * WW;
            const f4 m = *(const f4*)(row + w0);
            P[r][1] = m.x; P[r][2] = m.y; P[r][3] = m.z; P[r][4] = m.w;
            if (r != 1) { P[r][0] = row[wl]; }   // right halo never used
        }
    }

    float acc[8][4];
    #pragma unroll
    for (int q = 0; q < 4; ++q) {
        const float v = S[2][q + 1], u = S[1][q + 1];
        const float d10   = u           - v;
        const float dn10  = S[3][q + 1] - v;
        const float d01   = S[2][q]     - v;
        const float dn01  = S[2][q + 2] - v;
        const float d11   = S[1][q]     - v;
        const float dnn11 = S[3][q + 2] - v;
        const float dn11  = S[3][q]     - v;
        const float d1n1  = S[1][q + 2] - v;
        const float r_d10 = S[0][q + 1] - u;
        const float r_d01 = S[1][q]     - u;

        const float A01m   = M[2][q]     - M[2][q + 1];
        const float An01m  = M[2][q + 2] - M[2][q + 1];
        const float rA11m  = M[0][q]     - M[1][q + 1];
        const float rAn11m = M[2][q]     - M[1][q + 1];
        const float rA1n1m = M[0][q + 2] - M[1][q + 1];
        const float rA11p  = P[0][q]     - P[1][q + 1];
        const float rAn11p = P[2][q]     - P[1][q + 1];

        // shared Q factors: 2^(K*|diff|), one exp each (17 total)
        const float q10    = QE(d10),    qn10   = QE(dn10);
        const float q01    = QE(d01),    qn01   = QE(dn01);
        const float q11    = QE(d11),    qdn11  = QE(dn11);
        const float q1n1   = QE(d1n1),   qnn11  = QE(dnn11);
        const float qr10   = QE(r_d10),  qr01   = QE(r_d01);
        const float qA01m  = QE(A01m),   qAn01m = QE(An01m);
        const float qA11m  = QE(rA11m),  qAn11m = QE(rAn11m);
        const float qA1n1m = QE(rA1n1m);
        const float qA11p  = QE(rA11p),  qAn11p = QE(rAn11p);

        const float msk = ((w0 + q) >= 2 && (w0 + q) < WW - 2) ? 1.0f : 0.0f;

        // ---- branch 10 ----
        const float a10  = fabsf(d10);
        const float r10  = __builtin_amdgcn_rcpf(1.0f + q10);  // sigm(-a10)
        const float om10 = 1.0f - r10;                          // sigm(a10)
        const float ad10 = a10 * om10;
        const float P10  = __builtin_amdgcn_exp2f(-KSL * ad10);
        const float e10s = term(q01, P10) + term(qn01, P10) + term(qn10, P10)
                         + 2.0f * term(qA01m, P10)             // repeated in ref
                         + term(qAn01m, P10);
        const float g10 = msk * sig_arg(fmaf(e10s, -KSL, FOURK));
        const float s10 = (d10 >= 0.0f) ? om10 : r10;           // sigm(d10)
        acc[0][q] = g10 * s10;
        acc[1][q] = fmaf(-s10, g10, g10);                       // g*(1-s)

        // ---- branch 01 ---- (ref scales ad_01 by sigm(ad_10))
        const float sad10 = __builtin_amdgcn_rcpf(1.0f + P10);  // sigm(ad10)
        const float ad01  = fabsf(d01) * sad10;
        const float P01   = __builtin_amdgcn_exp2f(-KSL * ad01);
        const float e01s = 2.0f * term(q10, P01)                // term twice
                         + term(qn10, P01) + term(qn01, P01)
                         + term(qr10, P01) + term(qr01, P01);
        const float g01 = msk * sig_arg(fmaf(e01s, -KSL, FOURK));
        const float r01 = __builtin_amdgcn_rcpf(1.0f + q01);
        const float s01 = (d01 >= 0.0f) ? (1.0f - r01) : r01;   // sigm(d01)
        const float e01 = g01 * s01;
        acc[2][q] = e01;
        acc[3][q] = e01;                                        // ref: e01n == e01

        // ---- branch 11 ----
        const float a11  = fabsf(d11);
        const float r11  = __builtin_amdgcn_rcpf(1.0f + q11);
        const float om11 = 1.0f - r11;
        const float ad11 = a11 * om11;
        const float P11  = __builtin_amdgcn_exp2f(-KSL * ad11);
        const float e11s = term(qdn11, P11) + term(q1n1, P11) + term(qnn11, P11)
                         + term(qAn11m, P11) + term(qA1n1m, P11) + term(qA11m, P11);
        const float g11 = msk * sig_arg(fmaf(e11s, -KSL, FOURK));
        const float s11 = (d11 >= 0.0f) ? om11 : r11;
        acc[4][q] = g11 * s11;
        acc[5][q] = fmaf(-s11, g11, g11);

        // ---- branch n11 ---- (hard >0 mask is identity)
        const float Pn11 = __builtin_amdgcn_exp2f(-KSL * fabsf(dn11));
        const float en11s = term(q11, Pn11) + term(q1n1, Pn11) + term(qnn11, Pn11)
                          + term(qA11p, Pn11)
                          + 2.0f * term(qAn11p, Pn11);          // repeated
        const float gn11 = msk * sig_arg(fmaf(en11s, -KSL, FOURK));
        const float rn   = __builtin_amdgcn_rcpf(1.0f + qdn11);
        const float sn11 = (dn11 >= 0.0f) ? (1.0f - rn) : rn;
        acc[6][q] = gn11 * sn11;
        acc[7][q] = fmaf(-sn11, gn11, gn11);
    }

    #pragma unroll
    for (int k = 0; k < 8; ++k) {
        const f4 o = {acc[k][0], acc[k][1], acc[k][2], acc[k][3]};
        __builtin_nontemporal_store(o, (f4*)(outp + k * PL));
    }
}

extern "C" void kernel_launch(void* const* d_in, const int* in_sizes, int n_in,
                              void* d_out, int out_size, void* d_ws, size_t ws_size,
                              hipStream_t stream) {
    const float* x = (const float*)d_in[0];
    float* out = (float*)d_out;
    dim3 grid(WW / 256, HH / 4, 16 * 3);  // (2, 128, 48): z = b*3 + c
    dim3 block(256);
    edge_kernel<<<grid, block, 0, stream>>>(x, out);
}